// Round 12
// baseline (167.977 us; speedup 1.0000x reference)
//
#include <hip/hip_runtime.h>
#include <stdint.h>

// Problem constants: B=4, T=2048, D=1024, H=16, HS=64
typedef __attribute__((ext_vector_type(8))) short short8;
typedef __attribute__((ext_vector_type(4))) float f32x4;
typedef __attribute__((ext_vector_type(16))) float f32x16;

__device__ __forceinline__ unsigned short f2bf(float f) {
  unsigned u = __float_as_uint(f);
  u = u + 0x7FFFu + ((u >> 16) & 1u);  // RNE
  return (unsigned short)(u >> 16);
}
__device__ __forceinline__ unsigned cvtpk_bf16(float lo, float hi) {
  unsigned r;
  asm("v_cvt_pk_bf16_f32 %0, %1, %2" : "=v"(r) : "v"(lo), "v"(hi));
  return r;
}
__device__ __forceinline__ float fast_exp2(float x) {
#if __has_builtin(__builtin_amdgcn_exp2f)
  return __builtin_amdgcn_exp2f(x);
#else
  return exp2f(x);
#endif
}
// async global->LDS, 16B per lane; lds ptr wave-uniform (HW adds lane*16)
__device__ __forceinline__ void gl2lds16(const void* g, void* l) {
  __builtin_amdgcn_global_load_lds(
      (const __attribute__((address_space(1))) void*)(uintptr_t)g,
      (__attribute__((address_space(3))) void*)(uintptr_t)l, 16, 0, 0);
}

// ---------------- fused pack: x -> bf16; weights -> transposed bf16 ----------------
__global__ __launch_bounds__(256) void pack_all_kernel(const float* __restrict__ x,
                                                       const float* __restrict__ Wq,
                                                       const float* __restrict__ Wk,
                                                       const float* __restrict__ Wv,
                                                       const float* __restrict__ Wp,
                                                       ushort* __restrict__ xb,
                                                       ushort* __restrict__ WqkvT,
                                                       ushort* __restrict__ WpT) {
  __shared__ float tile[64][65];
  const int bid0 = blockIdx.x;
  const int tid = threadIdx.x;
  if (bid0 < 4096) {
    int i = (bid0 * 256 + tid) * 8;
    float4 a = *(const float4*)(x + i);
    float4 b = *(const float4*)(x + i + 4);
    uint4 o;
    o.x = (unsigned)f2bf(a.x) | ((unsigned)f2bf(a.y) << 16);
    o.y = (unsigned)f2bf(a.z) | ((unsigned)f2bf(a.w) << 16);
    o.z = (unsigned)f2bf(b.x) | ((unsigned)f2bf(b.y) << 16);
    o.w = (unsigned)f2bf(b.z) | ((unsigned)f2bf(b.w) << 16);
    *(uint4*)(xb + i) = o;
    return;
  }
  const int bid = bid0 - 4096;
  const int lr = tid >> 6;   // 0..3
  const int lc = tid & 63;   // 0..63
  if (bid < 768) {
    const int s = bid >> 8;
    const int rem = bid & 255;
    const int h = rem >> 4;
    const int dt = rem & 15;
    const float* W = (s == 0) ? Wq : (s == 1) ? Wk : Wv;
    const float scale = (s == 0) ? 0.18033688011f : 1.0f;  // 0.125 * log2(e)
#pragma unroll
    for (int p = 0; p < 16; ++p) {
      int r = p * 4 + lr;
      tile[r][lc] = W[(size_t)(h * 1024 + dt * 64 + r) * 64 + lc];
    }
    __syncthreads();
#pragma unroll
    for (int p = 0; p < 16; ++p) {
      int e = p * 4 + lr;
      float v = tile[lc][e] * scale;
      WqkvT[(size_t)(s * 1024 + h * 64 + e) * 1024 + dt * 64 + lc] = f2bf(v);
    }
  } else {
    const int t = bid - 768;
    const int rt = t >> 4, ct = t & 15;
#pragma unroll
    for (int p = 0; p < 16; ++p) {
      int r = p * 4 + lr;
      tile[r][lc] = Wp[(size_t)(rt * 64 + r) * 1024 + ct * 64 + lc];
    }
    __syncthreads();
#pragma unroll
    for (int p = 0; p < 16; ++p) {
      int c = p * 4 + lr;
      float v = tile[lc][c];
      WpT[(size_t)(ct * 64 + c) * 1024 + rt * 64 + lc] = f2bf(v);
    }
  }
}

// ---------------- bf16 MFMA GEMM: C[M,N] = A[M,K] * BT[N,K]^T ----------------
// 128x128 tile, BK=64 (128B LDS rows), 2-barrier skeleton, row-XOR swizzle
// (pre-swizzled gl2lds source + XOR frag read). r7-proven, ~858 TF.
template <int OUT_MODE>
__global__ __launch_bounds__(256) void gemm_bt(const ushort* __restrict__ A,
                                               const ushort* __restrict__ BT,
                                               ushort* __restrict__ Cb,
                                               float* __restrict__ Cf,
                                               const float* __restrict__ bias,
                                               int M, int N, int K) {
  __shared__ __align__(16) ushort Al[128 * 64];
  __shared__ __align__(16) ushort Bl[128 * 64];
  const int tid = threadIdx.x;
  const int lane = tid & 63;
  const int wave = tid >> 6;
  const int wm = wave >> 1, wn = wave & 1;
  const int nbx = gridDim.x;
  const int nwg = nbx * gridDim.y;
  int wg = blockIdx.y * nbx + blockIdx.x;
  wg = (wg & 7) * (nwg >> 3) + (wg >> 3);
  const int m0 = (wg / nbx) * 128, n0 = (wg % nbx) * 128;
  const int r16 = lane & 15, g = lane >> 4;
  f32x4 acc[4][4] = {};
  const int kTiles = K >> 6;
  const size_t ldb = (size_t)K * 2;
  const int srow = tid >> 3;                                    // 0..31
  const int scol = ((tid & 7) * 16) ^ (((tid >> 3) & 7) << 4);  // pre-swizzled src col
  const char* a_src = (const char*)A + (size_t)(m0 + srow) * ldb + scol;
  const char* b_src = (const char*)BT + (size_t)(n0 + srow) * ldb + scol;
  char* a_d = (char*)Al + wave * 1024;
  char* b_d = (char*)Bl + wave * 1024;
  const size_t row32 = (size_t)32 * ldb;
  for (int kt = 0; kt < kTiles; ++kt) {
    const size_t k0b = (size_t)kt * 128;
    if (kt) __syncthreads();
#pragma unroll
    for (int i = 0; i < 4; ++i) {
      gl2lds16(a_src + i * row32 + k0b, a_d + i * 4096);
      gl2lds16(b_src + i * row32 + k0b, b_d + i * 4096);
    }
    __syncthreads();
    short8 af[4][2], bf2[4][2];
#pragma unroll
    for (int i = 0; i < 4; ++i) {
      const int ra = (wm * 64 + i * 16 + r16) * 128;
      const int rb = (wn * 64 + i * 16 + r16) * 128;
      const int sw = (r16 & 7) << 4;
#pragma unroll
      for (int ks = 0; ks < 2; ++ks) {
        af[i][ks] = *(const short8*)((const char*)Al + ra + ((ks * 64 + g * 16) ^ sw));
        bf2[i][ks] = *(const short8*)((const char*)Bl + rb + ((ks * 64 + g * 16) ^ sw));
      }
    }
#pragma unroll
    for (int ks = 0; ks < 2; ++ks)
#pragma unroll
      for (int mi = 0; mi < 4; ++mi)
#pragma unroll
        for (int ni = 0; ni < 4; ++ni)
          acc[mi][ni] = __builtin_amdgcn_mfma_f32_16x16x32_bf16(af[mi][ks], bf2[ni][ks],
                                                                acc[mi][ni], 0, 0, 0);
  }
#pragma unroll
  for (int mi = 0; mi < 4; ++mi)
#pragma unroll
    for (int ni = 0; ni < 4; ++ni)
#pragma unroll
      for (int r = 0; r < 4; ++r) {
        int row = m0 + wm * 64 + mi * 16 + g * 4 + r;
        int col = n0 + wn * 64 + ni * 16 + r16;
        float v = acc[mi][ni][r];
        if (OUT_MODE == 0) {
          Cb[(size_t)row * N + col] = f2bf(v);
        } else {
          Cf[(size_t)row * N + col] = v + bias[col];
        }
      }
}

// ---------------- MFMA causal flash attention (swapped QK^T, 32x32) ----------------
// r8-proven skeleton with INTERLEAVED KV-SPLIT: grid (16,16,4) = 1024 WGs; WG
// (qtA, sp) processes key-blocks sp, sp+2, ... of BOTH tiles of the pair
// (15-qtA, qtA). Staging total unchanged; work uniform (17 blocks/WG); 4
// independent WGs/CU hide the serial QK->exp2->cvtpk->PV chain. Partials are
// UNNORMALIZED: o (bf16) to O0/O1, l (f32) to Lbuf; combine normalizes.
// FIX vs r11: flat z-stride 256 (was 512) -> bijective decode, b in [0,4).
__global__ __launch_bounds__(256) void attn_mfma_kernel(const ushort* __restrict__ QKV,
                                                        ushort* __restrict__ O0,
                                                        ushort* __restrict__ O1,
                                                        float* __restrict__ Lbuf) {
  int flat = blockIdx.z * 256 + blockIdx.y * 16 + blockIdx.x;  // 1024 WGs
  flat = (flat & 7) * 128 + (flat >> 3);  // XCD-chunked swizzle (bijective, 1024%8==0)
  const int qtA = flat & 7;
  const int sp = (flat >> 3) & 1;  // key-split index
  const int h = (flat >> 4) & 15;
  const int b = flat >> 8;         // 0..3
  ushort* Opart = sp ? O1 : O0;
  __shared__ __align__(16) ushort Kl[2][64 * 64];  // K rows, XOR-swizzled content
  __shared__ __align__(16) ushort VT[64 * 64];     // V^T [dim][key], swizzled
  const int tid = threadIdx.x;
  const int lane = tid & 63;
  const int wave = tid >> 6;
  const int lo5 = lane & 31;
  const int hi = lane >> 5;

  short8 ones;
#pragma unroll
  for (int i = 0; i < 8; ++i) ones[i] = (short)0x3F80;  // bf16 1.0

  const int k_key0 = wave * 16 + (lane >> 3);
  const int k_key1 = k_key0 + 8;
  const int ksrc_off0 = ((lane & 7) * 16) ^ ((k_key0 & 7) << 4);
  const int ksrc_off1 = ((lane & 7) * 16) ^ ((k_key1 & 7) << 4);
  const char* kgbase = (const char*)(QKV + ((size_t)b * 2048) * 3072 + 1024 + h * 64);
  const int kp2 = (tid & 31) * 2;
  const int dg = tid >> 5;
  const char* vgbase = (const char*)(QKV + ((size_t)b * 2048) * 3072 + 2048 + h * 64 + dg * 8);

#pragma unroll
  for (int ph = 0; ph < 2; ++ph) {
    const int qt = ph ? qtA : (15 - qtA);
    const int qbase = qt * 128 + wave * 32;
    const int qg = qbase + lo5;

    short8 qf[4];
    {
      const ushort* qp = QKV + ((size_t)(b * 2048 + qbase + lo5) * 3072) + h * 64 + hi * 8;
#pragma unroll
      for (int dc = 0; dc < 4; ++dc) qf[dc] = *(const short8*)(qp + dc * 16);
    }

    f32x16 o0 = {}, o1 = {}, lacc = {};
    const int nblk = qt * 2 + 2;  // this split handles blk = sp, sp+2, ... < nblk

    // prologue: V(sp) reg loads; then (after protecting Kl[0]) issue K(sp) DMA
    uint4 nv0, nv1;
    {
      const char* vp = vgbase + (size_t)(sp * 64 + kp2) * 6144;
      nv0 = *(const uint4*)(vp);
      nv1 = *(const uint4*)(vp + 6144);
    }
    __syncthreads();  // previous phase's readers of Kl[0] are done
    gl2lds16(kgbase + (size_t)(sp * 64 + k_key0) * 6144 + ksrc_off0,
             (char*)Kl[0] + wave * 2048);
    gl2lds16(kgbase + (size_t)(sp * 64 + k_key1) * 6144 + ksrc_off1,
             (char*)Kl[0] + wave * 2048 + 1024);

    int cur = 0;
    for (int blk = sp; blk < nblk; blk += 2) {
      const int s0 = blk * 64;
      __syncthreads();  // A: K(blk) DMA drained; previous iteration's LDS reads done
      {                 // stage V(blk) from prefetched regs (transposed, swizzled)
        const ushort* e0 = (const ushort*)&nv0;
        const ushort* e1 = (const ushort*)&nv1;
#pragma unroll
        for (int j = 0; j < 8; ++j) {
          const int row = dg * 8 + j;
          *(unsigned*)((char*)VT + row * 128 + ((kp2 * 2) ^ ((row & 7) << 4))) =
              (unsigned)e0[j] | ((unsigned)e1[j] << 16);
        }
      }
      __syncthreads();  // B: V writes visible (K(blk) visible since A)

      if (blk + 2 < nblk) {
        // issue K(blk+2) DMA now -> latency covered by this block's compute
        char* kd = (char*)Kl[cur ^ 1] + wave * 2048;
        gl2lds16(kgbase + (size_t)(s0 + 128 + k_key0) * 6144 + ksrc_off0, kd);
        gl2lds16(kgbase + (size_t)(s0 + 128 + k_key1) * 6144 + ksrc_off1, kd + 1024);
        // V(blk+2) reg prefetch
        const char* vp = vgbase + (size_t)(s0 + 128 + kp2) * 6144;
        nv0 = *(const uint4*)(vp);
        nv1 = *(const uint4*)(vp + 6144);
      }

      const ushort* Kb = Kl[cur];
#pragma unroll
      for (int g2 = 0; g2 < 2; ++g2) {
        const int ks = s0 + g2 * 32;
        if (ks > qbase + 31) continue;  // fully masked (wave-uniform)
        f32x16 s_acc = {};
        const int krow = g2 * 32 + lo5;
        const char* ksrc = (const char*)Kb + krow * 128;
        const int ksw = (krow & 7) << 4;
#pragma unroll
        for (int dc = 0; dc < 4; ++dc) {
          short8 kf = *(const short8*)(ksrc + ((dc * 32 + hi * 16) ^ ksw));
          s_acc = __builtin_amdgcn_mfma_f32_32x32x16_bf16(kf, qf[dc], s_acc, 0, 0, 0);
        }
        float p[16];
        if (ks + 31 > qbase) {  // straddling diagonal (wave-uniform branch)
          const int ksg = ks + 4 * hi;
#pragma unroll
          for (int r = 0; r < 16; ++r) {
            const int key_g = ksg + (r & 3) + 8 * (r >> 2);
            float pv = fast_exp2(s_acc[r]);
            p[r] = (key_g <= qg) ? pv : 0.f;
          }
        } else {
#pragma unroll
          for (int r = 0; r < 16; ++r) p[r] = fast_exp2(s_acc[r]);
        }
#pragma unroll
        for (int kc = 0; kc < 2; ++kc) {
          unsigned w0 = cvtpk_bf16(p[kc * 8 + 0], p[kc * 8 + 1]);
          unsigned w2 = cvtpk_bf16(p[kc * 8 + 4], p[kc * 8 + 5]);
          unsigned w1 = cvtpk_bf16(p[kc * 8 + 2], p[kc * 8 + 3]);
          unsigned w3 = cvtpk_bf16(p[kc * 8 + 6], p[kc * 8 + 7]);
          asm("v_permlane32_swap_b32 %0, %1" : "+v"(w0), "+v"(w2));
          asm("v_permlane32_swap_b32 %0, %1" : "+v"(w1), "+v"(w3));
          uint4 paw;
          paw.x = w0; paw.y = w1; paw.z = w2; paw.w = w3;
          short8 pa = *(short8*)&paw;
          const int kb = (g2 * 32 + kc * 16 + hi * 8) * 2;
          lacc = __builtin_amdgcn_mfma_f32_32x32x16_bf16(pa, ones, lacc, 0, 0, 0);
          {
            const int vrow = lo5;
            short8 vf =
                *(const short8*)((const char*)VT + vrow * 128 + (kb ^ ((vrow & 7) << 4)));
            o0 = __builtin_amdgcn_mfma_f32_32x32x16_bf16(pa, vf, o0, 0, 0, 0);
          }
          {
            const int vrow = 32 + lo5;
            short8 vf =
                *(const short8*)((const char*)VT + vrow * 128 + (kb ^ ((vrow & 7) << 4)));
            o1 = __builtin_amdgcn_mfma_f32_32x32x16_bf16(pa, vf, o1, 0, 0, 0);
          }
        }
      }
      cur ^= 1;
    }

    // epilogue: UNNORMALIZED partials + l (combine kernel normalizes)
#pragma unroll
    for (int r = 0; r < 16; ++r) {
      const int qr = (r & 3) + 8 * (r >> 2) + 4 * hi;
      const int grow = b * 2048 + qbase + qr;
      ushort* ob = Opart + ((size_t)grow * 1024) + h * 64 + lo5;
      ob[0] = f2bf(o0[r]);
      ob[32] = f2bf(o1[r]);
      if (lo5 == 0) Lbuf[sp * 131072 + grow * 16 + h] = lacc[r];
    }
  }
}

// ---------------- combine partials: O = (O + P1) / (l0 + l1) ----------------
__global__ __launch_bounds__(256) void combine_kernel(const ushort* __restrict__ P1,
                                                      const float* __restrict__ L,
                                                      ushort* __restrict__ O) {
  const int idx = (blockIdx.x * 256 + threadIdx.x) * 8;
  const int row = idx >> 10;
  const int hh = (idx >> 6) & 15;
  const float inv = 1.f / (L[row * 16 + hh] + L[131072 + row * 16 + hh]);
  uint4 a = *(const uint4*)(O + idx);
  uint4 b = *(const uint4*)(P1 + idx);
  const unsigned* au = (const unsigned*)&a;
  const unsigned* bu = (const unsigned*)&b;
  uint4 o;
  unsigned* ou = (unsigned*)&o;
#pragma unroll
  for (int i = 0; i < 4; ++i) {
    float a0 = __uint_as_float(au[i] << 16);
    float a1 = __uint_as_float(au[i] & 0xFFFF0000u);
    float b0 = __uint_as_float(bu[i] << 16);
    float b1 = __uint_as_float(bu[i] & 0xFFFF0000u);
    ou[i] = (unsigned)f2bf((a0 + b0) * inv) | ((unsigned)f2bf((a1 + b1) * inv) << 16);
  }
  *(uint4*)(O + idx) = o;
}

extern "C" void kernel_launch(void* const* d_in, const int* in_sizes, int n_in,
                              void* d_out, int out_size, void* d_ws, size_t ws_size,
                              hipStream_t stream) {
  const float* x = (const float*)d_in[0];
  const float* Wq = (const float*)d_in[1];
  const float* Wk = (const float*)d_in[2];
  const float* Wv = (const float*)d_in[3];
  const float* Wp = (const float*)d_in[4];
  const float* bp = (const float*)d_in[5];
  float* out = (float*)d_out;

  ushort* xb = (ushort*)d_ws;            // [8192,1024]; reused as attn s=1 partial
  ushort* WqkvT = xb + 8388608;          // [3072,1024]; reused as attn l partials
  ushort* WpT = WqkvT + 3145728;         // [1024,1024]
  ushort* QKV = WpT + 1048576;           // [8192,3072]
  ushort* O = QKV + 25165824;            // [8192,1024] (attn s=0 partial, then final)
  float* Lbuf = (float*)WqkvT;           // [2][8192][16] f32 = 1 MB

  pack_all_kernel<<<5120, 256, 0, stream>>>(x, Wq, Wk, Wv, Wp, xb, WqkvT, WpT);
  gemm_bt<0><<<dim3(24, 64), 256, 0, stream>>>(xb, WqkvT, QKV, nullptr, nullptr,
                                               8192, 3072, 1024);
  // xb and WqkvT are dead after gemm1 -> reuse for attn partials
  attn_mfma_kernel<<<dim3(16, 16, 4), 256, 0, stream>>>(QKV, O, xb, Lbuf);
  combine_kernel<<<4096, 256, 0, stream>>>(xb, Lbuf, O);
  gemm_bt<1><<<dim3(8, 64), 256, 0, stream>>>(O, WpT, nullptr, out, bp,
                                              8192, 1024, 1024);
}

// Round 13
// 157.295 us; speedup vs baseline: 1.0679x; 1.0679x over previous
//
#include <hip/hip_runtime.h>
#include <stdint.h>

// Problem constants: B=4, T=2048, D=1024, H=16, HS=64
typedef __attribute__((ext_vector_type(8))) short short8;
typedef __attribute__((ext_vector_type(4))) float f32x4;
typedef __attribute__((ext_vector_type(16))) float f32x16;

__device__ __forceinline__ unsigned short f2bf(float f) {
  unsigned u = __float_as_uint(f);
  u = u + 0x7FFFu + ((u >> 16) & 1u);  // RNE
  return (unsigned short)(u >> 16);
}
__device__ __forceinline__ unsigned cvtpk_bf16(float lo, float hi) {
  unsigned r;
  asm("v_cvt_pk_bf16_f32 %0, %1, %2" : "=v"(r) : "v"(lo), "v"(hi));
  return r;
}
__device__ __forceinline__ float fast_exp2(float x) {
#if __has_builtin(__builtin_amdgcn_exp2f)
  return __builtin_amdgcn_exp2f(x);
#else
  return exp2f(x);
#endif
}
// async global->LDS, 16B per lane; lds ptr wave-uniform (HW adds lane*16)
__device__ __forceinline__ void gl2lds16(const void* g, void* l) {
  __builtin_amdgcn_global_load_lds(
      (const __attribute__((address_space(1))) void*)(uintptr_t)g,
      (__attribute__((address_space(3))) void*)(uintptr_t)l, 16, 0, 0);
}

// ---------------- fused pack: x -> bf16; weights -> transposed bf16 ----------------
__global__ __launch_bounds__(256) void pack_all_kernel(const float* __restrict__ x,
                                                       const float* __restrict__ Wq,
                                                       const float* __restrict__ Wk,
                                                       const float* __restrict__ Wv,
                                                       const float* __restrict__ Wp,
                                                       ushort* __restrict__ xb,
                                                       ushort* __restrict__ WqkvT,
                                                       ushort* __restrict__ WpT) {
  __shared__ float tile[64][65];
  const int bid0 = blockIdx.x;
  const int tid = threadIdx.x;
  if (bid0 < 4096) {
    int i = (bid0 * 256 + tid) * 8;
    float4 a = *(const float4*)(x + i);
    float4 b = *(const float4*)(x + i + 4);
    uint4 o;
    o.x = (unsigned)f2bf(a.x) | ((unsigned)f2bf(a.y) << 16);
    o.y = (unsigned)f2bf(a.z) | ((unsigned)f2bf(a.w) << 16);
    o.z = (unsigned)f2bf(b.x) | ((unsigned)f2bf(b.y) << 16);
    o.w = (unsigned)f2bf(b.z) | ((unsigned)f2bf(b.w) << 16);
    *(uint4*)(xb + i) = o;
    return;
  }
  const int bid = bid0 - 4096;
  const int lr = tid >> 6;   // 0..3
  const int lc = tid & 63;   // 0..63
  if (bid < 768) {
    const int s = bid >> 8;
    const int rem = bid & 255;
    const int h = rem >> 4;
    const int dt = rem & 15;
    const float* W = (s == 0) ? Wq : (s == 1) ? Wk : Wv;
    const float scale = (s == 0) ? 0.18033688011f : 1.0f;  // 0.125 * log2(e)
#pragma unroll
    for (int p = 0; p < 16; ++p) {
      int r = p * 4 + lr;
      tile[r][lc] = W[(size_t)(h * 1024 + dt * 64 + r) * 64 + lc];
    }
    __syncthreads();
#pragma unroll
    for (int p = 0; p < 16; ++p) {
      int e = p * 4 + lr;
      float v = tile[lc][e] * scale;
      WqkvT[(size_t)(s * 1024 + h * 64 + e) * 1024 + dt * 64 + lc] = f2bf(v);
    }
  } else {
    const int t = bid - 768;
    const int rt = t >> 4, ct = t & 15;
#pragma unroll
    for (int p = 0; p < 16; ++p) {
      int r = p * 4 + lr;
      tile[r][lc] = Wp[(size_t)(rt * 64 + r) * 1024 + ct * 64 + lc];
    }
    __syncthreads();
#pragma unroll
    for (int p = 0; p < 16; ++p) {
      int c = p * 4 + lr;
      float v = tile[lc][c];
      WpT[(size_t)(ct * 64 + c) * 1024 + rt * 64 + lc] = f2bf(v);
    }
  }
}

// ---------------- bf16 MFMA GEMM: C[M,N] = A[M,K] * BT[N,K]^T ----------------
// 128x128 tile, BK=64 (128B LDS rows), 2-barrier skeleton, row-XOR swizzle
// (pre-swizzled gl2lds source + XOR frag read). r7-proven, ~858 TF
// (~= the guide's measured K=1024 practical ceiling, m248).
template <int OUT_MODE>
__global__ __launch_bounds__(256) void gemm_bt(const ushort* __restrict__ A,
                                               const ushort* __restrict__ BT,
                                               ushort* __restrict__ Cb,
                                               float* __restrict__ Cf,
                                               const float* __restrict__ bias,
                                               int M, int N, int K) {
  __shared__ __align__(16) ushort Al[128 * 64];
  __shared__ __align__(16) ushort Bl[128 * 64];
  const int tid = threadIdx.x;
  const int lane = tid & 63;
  const int wave = tid >> 6;
  const int wm = wave >> 1, wn = wave & 1;
  const int nbx = gridDim.x;
  const int nwg = nbx * gridDim.y;
  int wg = blockIdx.y * nbx + blockIdx.x;
  wg = (wg & 7) * (nwg >> 3) + (wg >> 3);
  const int m0 = (wg / nbx) * 128, n0 = (wg % nbx) * 128;
  const int r16 = lane & 15, g = lane >> 4;
  f32x4 acc[4][4] = {};
  const int kTiles = K >> 6;
  const size_t ldb = (size_t)K * 2;
  const int srow = tid >> 3;                                    // 0..31
  const int scol = ((tid & 7) * 16) ^ (((tid >> 3) & 7) << 4);  // pre-swizzled src col
  const char* a_src = (const char*)A + (size_t)(m0 + srow) * ldb + scol;
  const char* b_src = (const char*)BT + (size_t)(n0 + srow) * ldb + scol;
  char* a_d = (char*)Al + wave * 1024;
  char* b_d = (char*)Bl + wave * 1024;
  const size_t row32 = (size_t)32 * ldb;
  for (int kt = 0; kt < kTiles; ++kt) {
    const size_t k0b = (size_t)kt * 128;
    if (kt) __syncthreads();
#pragma unroll
    for (int i = 0; i < 4; ++i) {
      gl2lds16(a_src + i * row32 + k0b, a_d + i * 4096);
      gl2lds16(b_src + i * row32 + k0b, b_d + i * 4096);
    }
    __syncthreads();
    short8 af[4][2], bf2[4][2];
#pragma unroll
    for (int i = 0; i < 4; ++i) {
      const int ra = (wm * 64 + i * 16 + r16) * 128;
      const int rb = (wn * 64 + i * 16 + r16) * 128;
      const int sw = (r16 & 7) << 4;
#pragma unroll
      for (int ks = 0; ks < 2; ++ks) {
        af[i][ks] = *(const short8*)((const char*)Al + ra + ((ks * 64 + g * 16) ^ sw));
        bf2[i][ks] = *(const short8*)((const char*)Bl + rb + ((ks * 64 + g * 16) ^ sw));
      }
    }
#pragma unroll
    for (int ks = 0; ks < 2; ++ks)
#pragma unroll
      for (int mi = 0; mi < 4; ++mi)
#pragma unroll
        for (int ni = 0; ni < 4; ++ni)
          acc[mi][ni] = __builtin_amdgcn_mfma_f32_16x16x32_bf16(af[mi][ks], bf2[ni][ks],
                                                                acc[mi][ni], 0, 0, 0);
  }
#pragma unroll
  for (int mi = 0; mi < 4; ++mi)
#pragma unroll
    for (int ni = 0; ni < 4; ++ni)
#pragma unroll
      for (int r = 0; r < 4; ++r) {
        int row = m0 + wm * 64 + mi * 16 + g * 4 + r;
        int col = n0 + wn * 64 + ni * 16 + r16;
        float v = acc[mi][ni][r];
        if (OUT_MODE == 0) {
          Cb[(size_t)row * N + col] = f2bf(v);
        } else {
          Cf[(size_t)row * N + col] = v + bias[col];
        }
      }
}

// ---------------- MFMA causal flash attention (swapped QK^T, 32x32) ----------------
// EXACT r8 skeleton (best proven: attn 62.4us, total 154.4): 256 thr, 4 waves x
// 32 q-rows, grid 512, pairing 15-qtA/qtA, K double-buffer via gl2lds, V
// reg-prefetch + ds_write in the A->B window, l via mfma(pa, ones).
// ONLY change: s_setprio(1)/(0) around MFMA clusters (T5, m191: +4-7% attn).
__global__ __launch_bounds__(256) void attn_mfma_kernel(const ushort* __restrict__ QKV,
                                                        ushort* __restrict__ O) {
  int flat = blockIdx.z * 128 + blockIdx.y * 8 + blockIdx.x;
  flat = (flat & 7) * 64 + (flat >> 3);  // XCD-chunked swizzle
  const int qtA = flat & 7;
  const int h = (flat >> 3) & 15;
  const int b = flat >> 7;
  __shared__ __align__(16) ushort Kl[2][64 * 64];  // K rows, XOR-swizzled content
  __shared__ __align__(16) ushort VT[64 * 64];     // V^T [dim][key], swizzled
  const int tid = threadIdx.x;
  const int lane = tid & 63;
  const int wave = tid >> 6;
  const int lo5 = lane & 31;
  const int hi = lane >> 5;

  short8 ones;
#pragma unroll
  for (int i = 0; i < 8; ++i) ones[i] = (short)0x3F80;  // bf16 1.0

  const int k_key0 = wave * 16 + (lane >> 3);
  const int k_key1 = k_key0 + 8;
  const int ksrc_off0 = ((lane & 7) * 16) ^ ((k_key0 & 7) << 4);
  const int ksrc_off1 = ((lane & 7) * 16) ^ ((k_key1 & 7) << 4);
  const char* kgbase = (const char*)(QKV + ((size_t)b * 2048) * 3072 + 1024 + h * 64);
  const int kp2 = (tid & 31) * 2;
  const int dg = tid >> 5;
  const char* vgbase = (const char*)(QKV + ((size_t)b * 2048) * 3072 + 2048 + h * 64 + dg * 8);

#pragma unroll
  for (int ph = 0; ph < 2; ++ph) {
    const int qt = ph ? qtA : (15 - qtA);
    const int qbase = qt * 128 + wave * 32;
    const int qg = qbase + lo5;

    short8 qf[4];
    {
      const ushort* qp = QKV + ((size_t)(b * 2048 + qbase + lo5) * 3072) + h * 64 + hi * 8;
#pragma unroll
      for (int dc = 0; dc < 4; ++dc) qf[dc] = *(const short8*)(qp + dc * 16);
    }

    f32x16 o0 = {}, o1 = {}, lacc = {};
    const int nblk = qt * 2 + 2;

    // prologue: V(0) reg loads; then (after protecting Kl[0]) issue K(0) DMA
    uint4 nv0, nv1;
    {
      const char* vp = vgbase + (size_t)kp2 * 6144;
      nv0 = *(const uint4*)(vp);
      nv1 = *(const uint4*)(vp + 6144);
    }
    __syncthreads();  // previous phase's readers of Kl[0] are done
    gl2lds16(kgbase + (size_t)k_key0 * 6144 + ksrc_off0, (char*)Kl[0] + wave * 2048);
    gl2lds16(kgbase + (size_t)k_key1 * 6144 + ksrc_off1, (char*)Kl[0] + wave * 2048 + 1024);

    int cur = 0;
    for (int blk = 0; blk < nblk; ++blk) {
      const int s0 = blk * 64;
      __syncthreads();  // A: K(blk) DMA drained; block blk-1 LDS reads done
      {                 // stage V(blk) from prefetched regs (transposed, swizzled)
        const ushort* e0 = (const ushort*)&nv0;
        const ushort* e1 = (const ushort*)&nv1;
#pragma unroll
        for (int j = 0; j < 8; ++j) {
          const int row = dg * 8 + j;
          *(unsigned*)((char*)VT + row * 128 + ((kp2 * 2) ^ ((row & 7) << 4))) =
              (unsigned)e0[j] | ((unsigned)e1[j] << 16);
        }
      }
      __syncthreads();  // B: V writes visible (K(blk) visible since A)

      if (blk + 1 < nblk) {
        // issue K(blk+1) DMA now -> latency covered by this block's compute
        char* kd = (char*)Kl[cur ^ 1] + wave * 2048;
        gl2lds16(kgbase + (size_t)(s0 + 64 + k_key0) * 6144 + ksrc_off0, kd);
        gl2lds16(kgbase + (size_t)(s0 + 64 + k_key1) * 6144 + ksrc_off1, kd + 1024);
        // V(blk+1) reg prefetch
        const char* vp = vgbase + (size_t)(s0 + 64 + kp2) * 6144;
        nv0 = *(const uint4*)(vp);
        nv1 = *(const uint4*)(vp + 6144);
      }

      const ushort* Kb = Kl[cur];
#pragma unroll
      for (int g2 = 0; g2 < 2; ++g2) {
        const int ks = s0 + g2 * 32;
        if (ks > qbase + 31) continue;  // fully masked (wave-uniform)
        f32x16 s_acc = {};
        const int krow = g2 * 32 + lo5;
        const char* ksrc = (const char*)Kb + krow * 128;
        const int ksw = (krow & 7) << 4;
        __builtin_amdgcn_s_setprio(1);
#pragma unroll
        for (int dc = 0; dc < 4; ++dc) {
          short8 kf = *(const short8*)(ksrc + ((dc * 32 + hi * 16) ^ ksw));
          s_acc = __builtin_amdgcn_mfma_f32_32x32x16_bf16(kf, qf[dc], s_acc, 0, 0, 0);
        }
        __builtin_amdgcn_s_setprio(0);
        float p[16];
        if (ks + 31 > qbase) {  // straddling diagonal (wave-uniform branch)
          const int ksg = ks + 4 * hi;
#pragma unroll
          for (int r = 0; r < 16; ++r) {
            const int key_g = ksg + (r & 3) + 8 * (r >> 2);
            float pv = fast_exp2(s_acc[r]);
            p[r] = (key_g <= qg) ? pv : 0.f;
          }
        } else {
#pragma unroll
          for (int r = 0; r < 16; ++r) p[r] = fast_exp2(s_acc[r]);
        }
#pragma unroll
        for (int kc = 0; kc < 2; ++kc) {
          unsigned w0 = cvtpk_bf16(p[kc * 8 + 0], p[kc * 8 + 1]);
          unsigned w2 = cvtpk_bf16(p[kc * 8 + 4], p[kc * 8 + 5]);
          unsigned w1 = cvtpk_bf16(p[kc * 8 + 2], p[kc * 8 + 3]);
          unsigned w3 = cvtpk_bf16(p[kc * 8 + 6], p[kc * 8 + 7]);
          asm("v_permlane32_swap_b32 %0, %1" : "+v"(w0), "+v"(w2));
          asm("v_permlane32_swap_b32 %0, %1" : "+v"(w1), "+v"(w3));
          uint4 paw;
          paw.x = w0; paw.y = w1; paw.z = w2; paw.w = w3;
          short8 pa = *(short8*)&paw;
          const int kb = (g2 * 32 + kc * 16 + hi * 8) * 2;
          __builtin_amdgcn_s_setprio(1);
          lacc = __builtin_amdgcn_mfma_f32_32x32x16_bf16(pa, ones, lacc, 0, 0, 0);
          {
            const int vrow = lo5;
            short8 vf =
                *(const short8*)((const char*)VT + vrow * 128 + (kb ^ ((vrow & 7) << 4)));
            o0 = __builtin_amdgcn_mfma_f32_32x32x16_bf16(pa, vf, o0, 0, 0, 0);
          }
          {
            const int vrow = 32 + lo5;
            short8 vf =
                *(const short8*)((const char*)VT + vrow * 128 + (kb ^ ((vrow & 7) << 4)));
            o1 = __builtin_amdgcn_mfma_f32_32x32x16_bf16(pa, vf, o1, 0, 0, 0);
          }
          __builtin_amdgcn_s_setprio(0);
        }
      }
      cur ^= 1;
    }

#pragma unroll
    for (int r = 0; r < 16; ++r) {
      const int qr = (r & 3) + 8 * (r >> 2) + 4 * hi;
      const float li = 1.f / lacc[r];
      ushort* ob = O + ((size_t)(b * 2048 + qbase + qr) * 1024) + h * 64 + lo5;
      ob[0] = f2bf(o0[r] * li);
      ob[32] = f2bf(o1[r] * li);
    }
  }
}

extern "C" void kernel_launch(void* const* d_in, const int* in_sizes, int n_in,
                              void* d_out, int out_size, void* d_ws, size_t ws_size,
                              hipStream_t stream) {
  const float* x = (const float*)d_in[0];
  const float* Wq = (const float*)d_in[1];
  const float* Wk = (const float*)d_in[2];
  const float* Wv = (const float*)d_in[3];
  const float* Wp = (const float*)d_in[4];
  const float* bp = (const float*)d_in[5];
  float* out = (float*)d_out;

  ushort* xb = (ushort*)d_ws;            // [8192,1024]
  ushort* WqkvT = xb + 8388608;          // [3072,1024]
  ushort* WpT = WqkvT + 3145728;         // [1024,1024]
  ushort* QKV = WpT + 1048576;           // [8192,3072]
  ushort* O = QKV + 25165824;            // [8192,1024]

  pack_all_kernel<<<5120, 256, 0, stream>>>(x, Wq, Wk, Wv, Wp, xb, WqkvT, WpT);
  gemm_bt<0><<<dim3(24, 64), 256, 0, stream>>>(xb, WqkvT, QKV, nullptr, nullptr,
                                               8192, 3072, 1024);
  attn_mfma_kernel<<<dim3(8, 16, 4), 256, 0, stream>>>(QKV, O);
  gemm_bt<1><<<dim3(8, 64), 256, 0, stream>>>(O, WpT, nullptr, out, bp,
                                              8192, 1024, 1024);
}

// Round 14
// 155.290 us; speedup vs baseline: 1.0817x; 1.0129x over previous
//
#include <hip/hip_runtime.h>
#include <stdint.h>

// Problem constants: B=4, T=2048, D=1024, H=16, HS=64
typedef __attribute__((ext_vector_type(8))) short short8;
typedef __attribute__((ext_vector_type(4))) float f32x4;
typedef __attribute__((ext_vector_type(16))) float f32x16;

__device__ __forceinline__ unsigned short f2bf(float f) {
  unsigned u = __float_as_uint(f);
  u = u + 0x7FFFu + ((u >> 16) & 1u);  // RNE
  return (unsigned short)(u >> 16);
}
__device__ __forceinline__ unsigned cvtpk_bf16(float lo, float hi) {
  unsigned r;
  asm("v_cvt_pk_bf16_f32 %0, %1, %2" : "=v"(r) : "v"(lo), "v"(hi));
  return r;
}
__device__ __forceinline__ float fast_exp2(float x) {
#if __has_builtin(__builtin_amdgcn_exp2f)
  return __builtin_amdgcn_exp2f(x);
#else
  return exp2f(x);
#endif
}
// async global->LDS, 16B per lane; lds ptr wave-uniform (HW adds lane*16)
__device__ __forceinline__ void gl2lds16(const void* g, void* l) {
  __builtin_amdgcn_global_load_lds(
      (const __attribute__((address_space(1))) void*)(uintptr_t)g,
      (__attribute__((address_space(3))) void*)(uintptr_t)l, 16, 0, 0);
}

// ---------------- fused pack: x -> bf16; weights -> transposed bf16 ----------------
__global__ __launch_bounds__(256) void pack_all_kernel(const float* __restrict__ x,
                                                       const float* __restrict__ Wq,
                                                       const float* __restrict__ Wk,
                                                       const float* __restrict__ Wv,
                                                       const float* __restrict__ Wp,
                                                       ushort* __restrict__ xb,
                                                       ushort* __restrict__ WqkvT,
                                                       ushort* __restrict__ WpT) {
  __shared__ float tile[64][65];
  const int bid0 = blockIdx.x;
  const int tid = threadIdx.x;
  if (bid0 < 4096) {
    int i = (bid0 * 256 + tid) * 8;
    float4 a = *(const float4*)(x + i);
    float4 b = *(const float4*)(x + i + 4);
    uint4 o;
    o.x = (unsigned)f2bf(a.x) | ((unsigned)f2bf(a.y) << 16);
    o.y = (unsigned)f2bf(a.z) | ((unsigned)f2bf(a.w) << 16);
    o.z = (unsigned)f2bf(b.x) | ((unsigned)f2bf(b.y) << 16);
    o.w = (unsigned)f2bf(b.z) | ((unsigned)f2bf(b.w) << 16);
    *(uint4*)(xb + i) = o;
    return;
  }
  const int bid = bid0 - 4096;
  const int lr = tid >> 6;   // 0..3
  const int lc = tid & 63;   // 0..63
  if (bid < 768) {
    const int s = bid >> 8;
    const int rem = bid & 255;
    const int h = rem >> 4;
    const int dt = rem & 15;
    const float* W = (s == 0) ? Wq : (s == 1) ? Wk : Wv;
    const float scale = (s == 0) ? 0.18033688011f : 1.0f;  // 0.125 * log2(e)
#pragma unroll
    for (int p = 0; p < 16; ++p) {
      int r = p * 4 + lr;
      tile[r][lc] = W[(size_t)(h * 1024 + dt * 64 + r) * 64 + lc];
    }
    __syncthreads();
#pragma unroll
    for (int p = 0; p < 16; ++p) {
      int e = p * 4 + lr;
      float v = tile[lc][e] * scale;
      WqkvT[(size_t)(s * 1024 + h * 64 + e) * 1024 + dt * 64 + lc] = f2bf(v);
    }
  } else {
    const int t = bid - 768;
    const int rt = t >> 4, ct = t & 15;
#pragma unroll
    for (int p = 0; p < 16; ++p) {
      int r = p * 4 + lr;
      tile[r][lc] = Wp[(size_t)(rt * 64 + r) * 1024 + ct * 64 + lc];
    }
    __syncthreads();
#pragma unroll
    for (int p = 0; p < 16; ++p) {
      int c = p * 4 + lr;
      float v = tile[lc][c];
      WpT[(size_t)(ct * 64 + c) * 1024 + rt * 64 + lc] = f2bf(v);
    }
  }
}

// ---------------- bf16 MFMA GEMM: C[M,N] = A[M,K] * BT[N,K]^T ----------------
// 128x128 tile, BK=64 (128B LDS rows), 2-barrier skeleton, row-XOR swizzle
// (pre-swizzled gl2lds source + XOR frag read). r7-proven, ~858 TF
// (~= the guide's measured K=1024 practical ceiling, m248).
template <int OUT_MODE>
__global__ __launch_bounds__(256) void gemm_bt(const ushort* __restrict__ A,
                                               const ushort* __restrict__ BT,
                                               ushort* __restrict__ Cb,
                                               float* __restrict__ Cf,
                                               const float* __restrict__ bias,
                                               int M, int N, int K) {
  __shared__ __align__(16) ushort Al[128 * 64];
  __shared__ __align__(16) ushort Bl[128 * 64];
  const int tid = threadIdx.x;
  const int lane = tid & 63;
  const int wave = tid >> 6;
  const int wm = wave >> 1, wn = wave & 1;
  const int nbx = gridDim.x;
  const int nwg = nbx * gridDim.y;
  int wg = blockIdx.y * nbx + blockIdx.x;
  wg = (wg & 7) * (nwg >> 3) + (wg >> 3);
  const int m0 = (wg / nbx) * 128, n0 = (wg % nbx) * 128;
  const int r16 = lane & 15, g = lane >> 4;
  f32x4 acc[4][4] = {};
  const int kTiles = K >> 6;
  const size_t ldb = (size_t)K * 2;
  const int srow = tid >> 3;                                    // 0..31
  const int scol = ((tid & 7) * 16) ^ (((tid >> 3) & 7) << 4);  // pre-swizzled src col
  const char* a_src = (const char*)A + (size_t)(m0 + srow) * ldb + scol;
  const char* b_src = (const char*)BT + (size_t)(n0 + srow) * ldb + scol;
  char* a_d = (char*)Al + wave * 1024;
  char* b_d = (char*)Bl + wave * 1024;
  const size_t row32 = (size_t)32 * ldb;
  for (int kt = 0; kt < kTiles; ++kt) {
    const size_t k0b = (size_t)kt * 128;
    if (kt) __syncthreads();
#pragma unroll
    for (int i = 0; i < 4; ++i) {
      gl2lds16(a_src + i * row32 + k0b, a_d + i * 4096);
      gl2lds16(b_src + i * row32 + k0b, b_d + i * 4096);
    }
    __syncthreads();
    short8 af[4][2], bf2[4][2];
#pragma unroll
    for (int i = 0; i < 4; ++i) {
      const int ra = (wm * 64 + i * 16 + r16) * 128;
      const int rb = (wn * 64 + i * 16 + r16) * 128;
      const int sw = (r16 & 7) << 4;
#pragma unroll
      for (int ks = 0; ks < 2; ++ks) {
        af[i][ks] = *(const short8*)((const char*)Al + ra + ((ks * 64 + g * 16) ^ sw));
        bf2[i][ks] = *(const short8*)((const char*)Bl + rb + ((ks * 64 + g * 16) ^ sw));
      }
    }
#pragma unroll
    for (int ks = 0; ks < 2; ++ks)
#pragma unroll
      for (int mi = 0; mi < 4; ++mi)
#pragma unroll
        for (int ni = 0; ni < 4; ++ni)
          acc[mi][ni] = __builtin_amdgcn_mfma_f32_16x16x32_bf16(af[mi][ks], bf2[ni][ks],
                                                                acc[mi][ni], 0, 0, 0);
  }
#pragma unroll
  for (int mi = 0; mi < 4; ++mi)
#pragma unroll
    for (int ni = 0; ni < 4; ++ni)
#pragma unroll
      for (int r = 0; r < 4; ++r) {
        int row = m0 + wm * 64 + mi * 16 + g * 4 + r;
        int col = n0 + wn * 64 + ni * 16 + r16;
        float v = acc[mi][ni][r];
        if (OUT_MODE == 0) {
          Cb[(size_t)row * N + col] = f2bf(v);
        } else {
          Cf[(size_t)row * N + col] = v + bias[col];
        }
      }
}

// ---------------- MFMA causal flash attention (swapped QK^T, 32x32) ----------------
// r8 skeleton with KVBLK=128 (barrier rounds halve, 34 -> 17; r6's proven lever).
// 256 thr, 4 waves x 32 q-rows, grid 512, pairing 15-qtA/qtA. K double-buffered
// 2x16KB via gl2lds (pre-swizzled src, 4 issues/wave); V reg-prefetch (4xuint4)
// + 16 ds_write_b32 in the A->B window into VT[64][256B] with (row&15)<<4
// swizzle (vf reads now 2-way = free). l via mfma(pa, ones). Sync structure
// verbatim r8: K(blk) DMA drains at barrier A(blk); V writes visible at B.
__global__ __launch_bounds__(256) void attn_mfma_kernel(const ushort* __restrict__ QKV,
                                                        ushort* __restrict__ O) {
  int flat = blockIdx.z * 128 + blockIdx.y * 8 + blockIdx.x;
  flat = (flat & 7) * 64 + (flat >> 3);  // XCD-chunked swizzle
  const int qtA = flat & 7;
  const int h = (flat >> 3) & 15;
  const int b = flat >> 7;
  __shared__ __align__(16) ushort Kl[2][128 * 64];  // 2 x 16KB, K rows 128B
  __shared__ __align__(16) ushort VT[64 * 128];     // 16KB, rows=dim, 256B rows
  const int tid = threadIdx.x;
  const int lane = tid & 63;
  const int wave = tid >> 6;
  const int lo5 = lane & 31;
  const int hi = lane >> 5;

  short8 ones;
#pragma unroll
  for (int i = 0; i < 8; ++i) ones[i] = (short)0x3F80;  // bf16 1.0

  // K staging: issue i covers keys wave*32 + i*8 + (lane>>3); i*8 preserves key&7
  const int k_key0 = wave * 32 + (lane >> 3);
  const int ksrc_off = ((lane & 7) * 16) ^ ((k_key0 & 7) << 4);
  const char* kgbase = (const char*)(QKV + ((size_t)b * 2048) * 3072 + 1024 + h * 64);
  // V staging: thread owns keys (kp2, kp2+1) x dims dg*16..dg*16+15
  const int kp2 = (tid & 63) * 2;
  const int dg = tid >> 6;  // == wave
  const char* vgbase =
      (const char*)(QKV + ((size_t)b * 2048) * 3072 + 2048 + h * 64 + dg * 16);

#pragma unroll
  for (int ph = 0; ph < 2; ++ph) {
    const int qt = ph ? qtA : (15 - qtA);
    const int qbase = qt * 128 + wave * 32;
    const int qg = qbase + lo5;

    short8 qf[4];
    {
      const ushort* qp = QKV + ((size_t)(b * 2048 + qbase + lo5) * 3072) + h * 64 + hi * 8;
#pragma unroll
      for (int dc = 0; dc < 4; ++dc) qf[dc] = *(const short8*)(qp + dc * 16);
    }

    f32x16 o0 = {}, o1 = {}, lacc = {};
    const int nblk = qt + 1;  // 128-key blocks

    // prologue: V(0) reg loads; then (after protecting Kl[0]) issue K(0) DMA
    uint4 va0, va1, vb0, vb1;
    {
      const char* vp = vgbase + (size_t)kp2 * 6144;
      va0 = *(const uint4*)(vp);
      va1 = *(const uint4*)(vp + 16);
      vb0 = *(const uint4*)(vp + 6144);
      vb1 = *(const uint4*)(vp + 6144 + 16);
    }
    __syncthreads();  // previous phase's readers of Kl[0] are done
#pragma unroll
    for (int i = 0; i < 4; ++i)
      gl2lds16(kgbase + (size_t)(k_key0 + i * 8) * 6144 + ksrc_off,
               (char*)Kl[0] + wave * 4096 + i * 1024);

    int cur = 0;
    for (int blk = 0; blk < nblk; ++blk) {
      const int s0 = blk * 128;
      __syncthreads();  // A: K(blk) DMA drained; block blk-1 LDS reads done
      {                 // stage V(blk): transposed + swizzled, 16 b32 writes
        const ushort* ea0 = (const ushort*)&va0;
        const ushort* ea1 = (const ushort*)&va1;
        const ushort* eb0 = (const ushort*)&vb0;
        const ushort* eb1 = (const ushort*)&vb1;
#pragma unroll
        for (int j = 0; j < 8; ++j) {
          const int row = dg * 16 + j;
          *(unsigned*)((char*)VT + row * 256 + ((kp2 * 2) ^ ((row & 15) << 4))) =
              (unsigned)ea0[j] | ((unsigned)eb0[j] << 16);
        }
#pragma unroll
        for (int j = 0; j < 8; ++j) {
          const int row = dg * 16 + 8 + j;
          *(unsigned*)((char*)VT + row * 256 + ((kp2 * 2) ^ ((row & 15) << 4))) =
              (unsigned)ea1[j] | ((unsigned)eb1[j] << 16);
        }
      }
      __syncthreads();  // B: V writes visible (K(blk) visible since A)

      if (blk + 1 < nblk) {
        // issue K(blk+1) DMA now -> latency covered by this block's compute
        char* kd = (char*)Kl[cur ^ 1] + wave * 4096;
#pragma unroll
        for (int i = 0; i < 4; ++i)
          gl2lds16(kgbase + (size_t)(s0 + 128 + k_key0 + i * 8) * 6144 + ksrc_off,
                   kd + i * 1024);
        // V(blk+1) reg prefetch
        const char* vp = vgbase + (size_t)(s0 + 128 + kp2) * 6144;
        va0 = *(const uint4*)(vp);
        va1 = *(const uint4*)(vp + 16);
        vb0 = *(const uint4*)(vp + 6144);
        vb1 = *(const uint4*)(vp + 6144 + 16);
      }

      const ushort* Kb = Kl[cur];
#pragma unroll
      for (int g2 = 0; g2 < 4; ++g2) {
        const int ks = s0 + g2 * 32;
        if (ks > qbase + 31) continue;  // fully masked (wave-uniform)
        f32x16 s_acc = {};
        const int krow = g2 * 32 + lo5;
        const char* ksrc = (const char*)Kb + krow * 128;
        const int ksw = (krow & 7) << 4;
#pragma unroll
        for (int dc = 0; dc < 4; ++dc) {
          short8 kf = *(const short8*)(ksrc + ((dc * 32 + hi * 16) ^ ksw));
          s_acc = __builtin_amdgcn_mfma_f32_32x32x16_bf16(kf, qf[dc], s_acc, 0, 0, 0);
        }
        float p[16];
        if (ks + 31 > qbase) {  // straddling diagonal (wave-uniform branch)
          const int ksg = ks + 4 * hi;
#pragma unroll
          for (int r = 0; r < 16; ++r) {
            const int key_g = ksg + (r & 3) + 8 * (r >> 2);
            float pv = fast_exp2(s_acc[r]);
            p[r] = (key_g <= qg) ? pv : 0.f;
          }
        } else {
#pragma unroll
          for (int r = 0; r < 16; ++r) p[r] = fast_exp2(s_acc[r]);
        }
#pragma unroll
        for (int kc = 0; kc < 2; ++kc) {
          unsigned w0 = cvtpk_bf16(p[kc * 8 + 0], p[kc * 8 + 1]);
          unsigned w2 = cvtpk_bf16(p[kc * 8 + 4], p[kc * 8 + 5]);
          unsigned w1 = cvtpk_bf16(p[kc * 8 + 2], p[kc * 8 + 3]);
          unsigned w3 = cvtpk_bf16(p[kc * 8 + 6], p[kc * 8 + 7]);
          asm("v_permlane32_swap_b32 %0, %1" : "+v"(w0), "+v"(w2));
          asm("v_permlane32_swap_b32 %0, %1" : "+v"(w1), "+v"(w3));
          uint4 paw;
          paw.x = w0; paw.y = w1; paw.z = w2; paw.w = w3;
          short8 pa = *(short8*)&paw;
          const int kb = (g2 * 32 + kc * 16 + hi * 8) * 2;  // byte offset in 256B row
          lacc = __builtin_amdgcn_mfma_f32_32x32x16_bf16(pa, ones, lacc, 0, 0, 0);
          {
            const int vrow = lo5;
            short8 vf =
                *(const short8*)((const char*)VT + vrow * 256 + (kb ^ ((vrow & 15) << 4)));
            o0 = __builtin_amdgcn_mfma_f32_32x32x16_bf16(pa, vf, o0, 0, 0, 0);
          }
          {
            const int vrow = 32 + lo5;
            short8 vf =
                *(const short8*)((const char*)VT + vrow * 256 + (kb ^ ((vrow & 15) << 4)));
            o1 = __builtin_amdgcn_mfma_f32_32x32x16_bf16(pa, vf, o1, 0, 0, 0);
          }
        }
      }
      cur ^= 1;
    }

#pragma unroll
    for (int r = 0; r < 16; ++r) {
      const int qr = (r & 3) + 8 * (r >> 2) + 4 * hi;
      const float li = 1.f / lacc[r];
      ushort* ob = O + ((size_t)(b * 2048 + qbase + qr) * 1024) + h * 64 + lo5;
      ob[0] = f2bf(o0[r] * li);
      ob[32] = f2bf(o1[r] * li);
    }
  }
}

extern "C" void kernel_launch(void* const* d_in, const int* in_sizes, int n_in,
                              void* d_out, int out_size, void* d_ws, size_t ws_size,
                              hipStream_t stream) {
  const float* x = (const float*)d_in[0];
  const float* Wq = (const float*)d_in[1];
  const float* Wk = (const float*)d_in[2];
  const float* Wv = (const float*)d_in[3];
  const float* Wp = (const float*)d_in[4];
  const float* bp = (const float*)d_in[5];
  float* out = (float*)d_out;

  ushort* xb = (ushort*)d_ws;            // [8192,1024]
  ushort* WqkvT = xb + 8388608;          // [3072,1024]
  ushort* WpT = WqkvT + 3145728;         // [1024,1024]
  ushort* QKV = WpT + 1048576;           // [8192,3072]
  ushort* O = QKV + 25165824;            // [8192,1024]

  pack_all_kernel<<<5120, 256, 0, stream>>>(x, Wq, Wk, Wv, Wp, xb, WqkvT, WpT);
  gemm_bt<0><<<dim3(24, 64), 256, 0, stream>>>(xb, WqkvT, QKV, nullptr, nullptr,
                                               8192, 3072, 1024);
  attn_mfma_kernel<<<dim3(8, 16, 4), 256, 0, stream>>>(QKV, O);
  gemm_bt<1><<<dim3(8, 64), 256, 0, stream>>>(O, WpT, nullptr, out, bp,
                                              8192, 1024, 1024);
}

// Round 15
// 154.798 us; speedup vs baseline: 1.0851x; 1.0032x over previous
//
#include <hip/hip_runtime.h>
#include <stdint.h>

// Problem constants: B=4, T=2048, D=1024, H=16, HS=64
typedef __attribute__((ext_vector_type(8))) short short8;
typedef __attribute__((ext_vector_type(4))) float f32x4;
typedef __attribute__((ext_vector_type(16))) float f32x16;

__device__ __forceinline__ unsigned short f2bf(float f) {
  unsigned u = __float_as_uint(f);
  u = u + 0x7FFFu + ((u >> 16) & 1u);  // RNE
  return (unsigned short)(u >> 16);
}
__device__ __forceinline__ unsigned cvtpk_bf16(float lo, float hi) {
  unsigned r;
  asm("v_cvt_pk_bf16_f32 %0, %1, %2" : "=v"(r) : "v"(lo), "v"(hi));
  return r;
}
__device__ __forceinline__ float fast_exp2(float x) {
#if __has_builtin(__builtin_amdgcn_exp2f)
  return __builtin_amdgcn_exp2f(x);
#else
  return exp2f(x);
#endif
}
// async global->LDS, 16B per lane; lds ptr wave-uniform (HW adds lane*16)
__device__ __forceinline__ void gl2lds16(const void* g, void* l) {
  __builtin_amdgcn_global_load_lds(
      (const __attribute__((address_space(1))) void*)(uintptr_t)g,
      (__attribute__((address_space(3))) void*)(uintptr_t)l, 16, 0, 0);
}

// ---------------- fused pack: x -> bf16; weights -> transposed bf16 ----------------
__global__ __launch_bounds__(256) void pack_all_kernel(const float* __restrict__ x,
                                                       const float* __restrict__ Wq,
                                                       const float* __restrict__ Wk,
                                                       const float* __restrict__ Wv,
                                                       const float* __restrict__ Wp,
                                                       ushort* __restrict__ xb,
                                                       ushort* __restrict__ WqkvT,
                                                       ushort* __restrict__ WpT) {
  __shared__ float tile[64][65];
  const int bid0 = blockIdx.x;
  const int tid = threadIdx.x;
  if (bid0 < 4096) {
    int i = (bid0 * 256 + tid) * 8;
    float4 a = *(const float4*)(x + i);
    float4 b = *(const float4*)(x + i + 4);
    uint4 o;
    o.x = (unsigned)f2bf(a.x) | ((unsigned)f2bf(a.y) << 16);
    o.y = (unsigned)f2bf(a.z) | ((unsigned)f2bf(a.w) << 16);
    o.z = (unsigned)f2bf(b.x) | ((unsigned)f2bf(b.y) << 16);
    o.w = (unsigned)f2bf(b.z) | ((unsigned)f2bf(b.w) << 16);
    *(uint4*)(xb + i) = o;
    return;
  }
  const int bid = bid0 - 4096;
  const int lr = tid >> 6;   // 0..3
  const int lc = tid & 63;   // 0..63
  if (bid < 768) {
    const int s = bid >> 8;
    const int rem = bid & 255;
    const int h = rem >> 4;
    const int dt = rem & 15;
    const float* W = (s == 0) ? Wq : (s == 1) ? Wk : Wv;
    const float scale = (s == 0) ? 0.18033688011f : 1.0f;  // 0.125 * log2(e)
#pragma unroll
    for (int p = 0; p < 16; ++p) {
      int r = p * 4 + lr;
      tile[r][lc] = W[(size_t)(h * 1024 + dt * 64 + r) * 64 + lc];
    }
    __syncthreads();
#pragma unroll
    for (int p = 0; p < 16; ++p) {
      int e = p * 4 + lr;
      float v = tile[lc][e] * scale;
      WqkvT[(size_t)(s * 1024 + h * 64 + e) * 1024 + dt * 64 + lc] = f2bf(v);
    }
  } else {
    const int t = bid - 768;
    const int rt = t >> 4, ct = t & 15;
#pragma unroll
    for (int p = 0; p < 16; ++p) {
      int r = p * 4 + lr;
      tile[r][lc] = Wp[(size_t)(rt * 64 + r) * 1024 + ct * 64 + lc];
    }
    __syncthreads();
#pragma unroll
    for (int p = 0; p < 16; ++p) {
      int c = p * 4 + lr;
      float v = tile[lc][c];
      WpT[(size_t)(ct * 64 + c) * 1024 + rt * 64 + lc] = f2bf(v);
    }
  }
}

// ---------------- bf16 MFMA GEMM: C[M,N] = A[M,K] * BT[N,K]^T ----------------
// 128x128 tile, BK=64 (128B LDS rows), 2-barrier skeleton, row-XOR swizzle
// (pre-swizzled gl2lds source + XOR frag read). r7-proven, ~858 TF
// (~= the guide's measured K=1024 practical ceiling, m248).
template <int OUT_MODE>
__global__ __launch_bounds__(256) void gemm_bt(const ushort* __restrict__ A,
                                               const ushort* __restrict__ BT,
                                               ushort* __restrict__ Cb,
                                               float* __restrict__ Cf,
                                               const float* __restrict__ bias,
                                               int M, int N, int K) {
  __shared__ __align__(16) ushort Al[128 * 64];
  __shared__ __align__(16) ushort Bl[128 * 64];
  const int tid = threadIdx.x;
  const int lane = tid & 63;
  const int wave = tid >> 6;
  const int wm = wave >> 1, wn = wave & 1;
  const int nbx = gridDim.x;
  const int nwg = nbx * gridDim.y;
  int wg = blockIdx.y * nbx + blockIdx.x;
  wg = (wg & 7) * (nwg >> 3) + (wg >> 3);
  const int m0 = (wg / nbx) * 128, n0 = (wg % nbx) * 128;
  const int r16 = lane & 15, g = lane >> 4;
  f32x4 acc[4][4] = {};
  const int kTiles = K >> 6;
  const size_t ldb = (size_t)K * 2;
  const int srow = tid >> 3;                                    // 0..31
  const int scol = ((tid & 7) * 16) ^ (((tid >> 3) & 7) << 4);  // pre-swizzled src col
  const char* a_src = (const char*)A + (size_t)(m0 + srow) * ldb + scol;
  const char* b_src = (const char*)BT + (size_t)(n0 + srow) * ldb + scol;
  char* a_d = (char*)Al + wave * 1024;
  char* b_d = (char*)Bl + wave * 1024;
  const size_t row32 = (size_t)32 * ldb;
  for (int kt = 0; kt < kTiles; ++kt) {
    const size_t k0b = (size_t)kt * 128;
    if (kt) __syncthreads();
#pragma unroll
    for (int i = 0; i < 4; ++i) {
      gl2lds16(a_src + i * row32 + k0b, a_d + i * 4096);
      gl2lds16(b_src + i * row32 + k0b, b_d + i * 4096);
    }
    __syncthreads();
    short8 af[4][2], bf2[4][2];
#pragma unroll
    for (int i = 0; i < 4; ++i) {
      const int ra = (wm * 64 + i * 16 + r16) * 128;
      const int rb = (wn * 64 + i * 16 + r16) * 128;
      const int sw = (r16 & 7) << 4;
#pragma unroll
      for (int ks = 0; ks < 2; ++ks) {
        af[i][ks] = *(const short8*)((const char*)Al + ra + ((ks * 64 + g * 16) ^ sw));
        bf2[i][ks] = *(const short8*)((const char*)Bl + rb + ((ks * 64 + g * 16) ^ sw));
      }
    }
#pragma unroll
    for (int ks = 0; ks < 2; ++ks)
#pragma unroll
      for (int mi = 0; mi < 4; ++mi)
#pragma unroll
        for (int ni = 0; ni < 4; ++ni)
          acc[mi][ni] = __builtin_amdgcn_mfma_f32_16x16x32_bf16(af[mi][ks], bf2[ni][ks],
                                                                acc[mi][ni], 0, 0, 0);
  }
#pragma unroll
  for (int mi = 0; mi < 4; ++mi)
#pragma unroll
    for (int ni = 0; ni < 4; ++ni)
#pragma unroll
      for (int r = 0; r < 4; ++r) {
        int row = m0 + wm * 64 + mi * 16 + g * 4 + r;
        int col = n0 + wn * 64 + ni * 16 + r16;
        float v = acc[mi][ni][r];
        if (OUT_MODE == 0) {
          Cb[(size_t)row * N + col] = f2bf(v);
        } else {
          Cf[(size_t)row * N + col] = v + bias[col];
        }
      }
}

// ---------------- MFMA causal flash attention (swapped QK^T, 32x32) ----------------
// EXACT r8 configuration (best proven: attn 62.4us, total 154.4): 256 thr,
// 4 waves x 32 q-rows, 128-row Q-tiles, grid 512, pairing 15-qtA/qtA (uniform
// 34 key-blocks/WG), KVBLK=64. K double-buffered via gl2lds (pre-swizzled
// source, linear LDS dest; K(blk+1) issued after barrier B, drains at barrier
// A(blk+1) hidden under compute). V single-buffered: reg-prefetch during
// compute, ds_write in the A->B window. l via mfma(pa, ones) -> row-aligned
// with o0/o1, no epilogue shuffles. Scores in exp2 units (Wq pre-scaled);
// fully-masked g2 skipped; mask only on the straddling g2 (wave-uniform).
__global__ __launch_bounds__(256) void attn_mfma_kernel(const ushort* __restrict__ QKV,
                                                        ushort* __restrict__ O) {
  int flat = blockIdx.z * 128 + blockIdx.y * 8 + blockIdx.x;
  flat = (flat & 7) * 64 + (flat >> 3);  // XCD-chunked swizzle
  const int qtA = flat & 7;
  const int h = (flat >> 3) & 15;
  const int b = flat >> 7;
  __shared__ __align__(16) ushort Kl[2][64 * 64];  // K rows, XOR-swizzled content
  __shared__ __align__(16) ushort VT[64 * 64];     // V^T [dim][key], swizzled
  const int tid = threadIdx.x;
  const int lane = tid & 63;
  const int wave = tid >> 6;
  const int lo5 = lane & 31;
  const int hi = lane >> 5;

  short8 ones;
#pragma unroll
  for (int i = 0; i < 8; ++i) ones[i] = (short)0x3F80;  // bf16 1.0

  const int k_key0 = wave * 16 + (lane >> 3);
  const int k_key1 = k_key0 + 8;
  const int ksrc_off0 = ((lane & 7) * 16) ^ ((k_key0 & 7) << 4);
  const int ksrc_off1 = ((lane & 7) * 16) ^ ((k_key1 & 7) << 4);
  const char* kgbase = (const char*)(QKV + ((size_t)b * 2048) * 3072 + 1024 + h * 64);
  const int kp2 = (tid & 31) * 2;
  const int dg = tid >> 5;
  const char* vgbase = (const char*)(QKV + ((size_t)b * 2048) * 3072 + 2048 + h * 64 + dg * 8);

#pragma unroll
  for (int ph = 0; ph < 2; ++ph) {
    const int qt = ph ? qtA : (15 - qtA);
    const int qbase = qt * 128 + wave * 32;
    const int qg = qbase + lo5;

    short8 qf[4];
    {
      const ushort* qp = QKV + ((size_t)(b * 2048 + qbase + lo5) * 3072) + h * 64 + hi * 8;
#pragma unroll
      for (int dc = 0; dc < 4; ++dc) qf[dc] = *(const short8*)(qp + dc * 16);
    }

    f32x16 o0 = {}, o1 = {}, lacc = {};
    const int nblk = qt * 2 + 2;

    // prologue: V(0) reg loads; then (after protecting Kl[0]) issue K(0) DMA
    uint4 nv0, nv1;
    {
      const char* vp = vgbase + (size_t)kp2 * 6144;
      nv0 = *(const uint4*)(vp);
      nv1 = *(const uint4*)(vp + 6144);
    }
    __syncthreads();  // previous phase's readers of Kl[0] are done
    gl2lds16(kgbase + (size_t)k_key0 * 6144 + ksrc_off0, (char*)Kl[0] + wave * 2048);
    gl2lds16(kgbase + (size_t)k_key1 * 6144 + ksrc_off1, (char*)Kl[0] + wave * 2048 + 1024);

    int cur = 0;
    for (int blk = 0; blk < nblk; ++blk) {
      const int s0 = blk * 64;
      __syncthreads();  // A: K(blk) DMA drained; block blk-1 LDS reads done
      {                 // stage V(blk) from prefetched regs (transposed, swizzled)
        const ushort* e0 = (const ushort*)&nv0;
        const ushort* e1 = (const ushort*)&nv1;
#pragma unroll
        for (int j = 0; j < 8; ++j) {
          const int row = dg * 8 + j;
          *(unsigned*)((char*)VT + row * 128 + ((kp2 * 2) ^ ((row & 7) << 4))) =
              (unsigned)e0[j] | ((unsigned)e1[j] << 16);
        }
      }
      __syncthreads();  // B: V writes visible (K(blk) visible since A)

      if (blk + 1 < nblk) {
        // issue K(blk+1) DMA now -> latency covered by this block's compute
        char* kd = (char*)Kl[cur ^ 1] + wave * 2048;
        gl2lds16(kgbase + (size_t)(s0 + 64 + k_key0) * 6144 + ksrc_off0, kd);
        gl2lds16(kgbase + (size_t)(s0 + 64 + k_key1) * 6144 + ksrc_off1, kd + 1024);
        // V(blk+1) reg prefetch
        const char* vp = vgbase + (size_t)(s0 + 64 + kp2) * 6144;
        nv0 = *(const uint4*)(vp);
        nv1 = *(const uint4*)(vp + 6144);
      }

      const ushort* Kb = Kl[cur];
#pragma unroll
      for (int g2 = 0; g2 < 2; ++g2) {
        const int ks = s0 + g2 * 32;
        if (ks > qbase + 31) continue;  // fully masked (wave-uniform)
        f32x16 s_acc = {};
        const int krow = g2 * 32 + lo5;
        const char* ksrc = (const char*)Kb + krow * 128;
        const int ksw = (krow & 7) << 4;
#pragma unroll
        for (int dc = 0; dc < 4; ++dc) {
          short8 kf = *(const short8*)(ksrc + ((dc * 32 + hi * 16) ^ ksw));
          s_acc = __builtin_amdgcn_mfma_f32_32x32x16_bf16(kf, qf[dc], s_acc, 0, 0, 0);
        }
        float p[16];
        if (ks + 31 > qbase) {  // straddling diagonal (wave-uniform branch)
          const int ksg = ks + 4 * hi;
#pragma unroll
          for (int r = 0; r < 16; ++r) {
            const int key_g = ksg + (r & 3) + 8 * (r >> 2);
            float pv = fast_exp2(s_acc[r]);
            p[r] = (key_g <= qg) ? pv : 0.f;
          }
        } else {
#pragma unroll
          for (int r = 0; r < 16; ++r) p[r] = fast_exp2(s_acc[r]);
        }
#pragma unroll
        for (int kc = 0; kc < 2; ++kc) {
          unsigned w0 = cvtpk_bf16(p[kc * 8 + 0], p[kc * 8 + 1]);
          unsigned w2 = cvtpk_bf16(p[kc * 8 + 4], p[kc * 8 + 5]);
          unsigned w1 = cvtpk_bf16(p[kc * 8 + 2], p[kc * 8 + 3]);
          unsigned w3 = cvtpk_bf16(p[kc * 8 + 6], p[kc * 8 + 7]);
          asm("v_permlane32_swap_b32 %0, %1" : "+v"(w0), "+v"(w2));
          asm("v_permlane32_swap_b32 %0, %1" : "+v"(w1), "+v"(w3));
          uint4 paw;
          paw.x = w0; paw.y = w1; paw.z = w2; paw.w = w3;
          short8 pa = *(short8*)&paw;
          const int kb = (g2 * 32 + kc * 16 + hi * 8) * 2;
          lacc = __builtin_amdgcn_mfma_f32_32x32x16_bf16(pa, ones, lacc, 0, 0, 0);
          {
            const int vrow = lo5;
            short8 vf =
                *(const short8*)((const char*)VT + vrow * 128 + (kb ^ ((vrow & 7) << 4)));
            o0 = __builtin_amdgcn_mfma_f32_32x32x16_bf16(pa, vf, o0, 0, 0, 0);
          }
          {
            const int vrow = 32 + lo5;
            short8 vf =
                *(const short8*)((const char*)VT + vrow * 128 + (kb ^ ((vrow & 7) << 4)));
            o1 = __builtin_amdgcn_mfma_f32_32x32x16_bf16(pa, vf, o1, 0, 0, 0);
          }
        }
      }
      cur ^= 1;
    }

#pragma unroll
    for (int r = 0; r < 16; ++r) {
      const int qr = (r & 3) + 8 * (r >> 2) + 4 * hi;
      const float li = 1.f / lacc[r];
      ushort* ob = O + ((size_t)(b * 2048 + qbase + qr) * 1024) + h * 64 + lo5;
      ob[0] = f2bf(o0[r] * li);
      ob[32] = f2bf(o1[r] * li);
    }
  }
}

extern "C" void kernel_launch(void* const* d_in, const int* in_sizes, int n_in,
                              void* d_out, int out_size, void* d_ws, size_t ws_size,
                              hipStream_t stream) {
  const float* x = (const float*)d_in[0];
  const float* Wq = (const float*)d_in[1];
  const float* Wk = (const float*)d_in[2];
  const float* Wv = (const float*)d_in[3];
  const float* Wp = (const float*)d_in[4];
  const float* bp = (const float*)d_in[5];
  float* out = (float*)d_out;

  ushort* xb = (ushort*)d_ws;            // [8192,1024]
  ushort* WqkvT = xb + 8388608;          // [3072,1024]
  ushort* WpT = WqkvT + 3145728;         // [1024,1024]
  ushort* QKV = WpT + 1048576;           // [8192,3072]
  ushort* O = QKV + 25165824;            // [8192,1024]

  pack_all_kernel<<<5120, 256, 0, stream>>>(x, Wq, Wk, Wv, Wp, xb, WqkvT, WpT);
  gemm_bt<0><<<dim3(24, 64), 256, 0, stream>>>(xb, WqkvT, QKV, nullptr, nullptr,
                                               8192, 3072, 1024);
  attn_mfma_kernel<<<dim3(8, 16, 4), 256, 0, stream>>>(QKV, O);
  gemm_bt<1><<<dim3(8, 64), 256, 0, stream>>>(O, WpT, nullptr, out, bp,
                                              8192, 1024, 1024);
}